// Round 9
// baseline (202.126 us; speedup 1.0000x reference)
//
#include <hip/hip_runtime.h>
#include <hip/hip_cooperative_groups.h>
#include <stdint.h>

namespace cg = cooperative_groups;

#define N_ANCH 67200
#define KCAP   1000
#define CONF_THR 0.7f
#define NMS_THR  0.4f

// score-bits histogram: scores in (0.7, 1.0] -> bits in (0x3F333333, 0x3F800000]
// span = 0x4CCCCD ulp; shift 10 -> 4917 live buckets; NBUCK = 5120 = 1024*5.
#define BUCK_BASE 0x3F333333u
#define BUCK_SHIFT 10
#define NBUCK 5120
#define CAPG 4096             // bucket-sorted key capacity (kept ~ 1010)

#define NBLK 66
#define NTHR 1024
#define GSZ  (NBLK * NTHR)    // 67584 >= N_ANCH

// ---- workspace layout (bytes), ~801 KB total ----
#define OFF_CTR   0
#define OFF_HIST  64
#define OFF_FILL  (OFF_HIST + NBUCK * 4)     // 20544
#define OFF_LIST  (OFF_FILL + NBUCK * 4)     // 41024
#define OFF_GKEYS (OFF_LIST + N_ANCH * 8)    // 578624
#define OFF_SCORE (OFF_GKEYS + CAPG * 8)     // 611392
#define OFF_BOX   (OFF_SCORE + 4096)         // 615488
#define OFF_LM    (OFF_BOX + 16384)          // 631872
#define OFF_SUP   (OFF_LM + 40960)           // 672832 (+128000 = 800832)

__device__ inline unsigned long long shfl_xor_u64(unsigned long long v, int m) {
    unsigned int lo = (unsigned int)__shfl_xor((int)(v & 0xffffffffull), m, 64);
    unsigned int hi = (unsigned int)__shfl_xor((int)(v >> 32), m, 64);
    return ((unsigned long long)hi << 32) | lo;
}

// Single cooperative kernel: zero -> front -> (per-block) findcut+scan ->
// scatter -> rank+decode -> sup -> scan+output, grid.sync() between phases.
__global__ __launch_bounds__(NTHR, 1) void k_all(
        const float* __restrict__ loc,
        const float* __restrict__ conf,
        const float* __restrict__ land,
        const float* __restrict__ priors,
        float* __restrict__ out,
        char* __restrict__ ws) {
#pragma clang fp contract(off)
    cg::grid_group grid = cg::this_grid();
    int* ctr   = (int*)(ws + OFF_CTR);
    int* hist  = (int*)(ws + OFF_HIST);
    int* gfill = (int*)(ws + OFF_FILL);
    unsigned long long* list  = (unsigned long long*)(ws + OFF_LIST);
    unsigned long long* gkeys = (unsigned long long*)(ws + OFF_GKEYS);
    float* sel_score          = (float*)(ws + OFF_SCORE);
    float* sel_box            = (float*)(ws + OFF_BOX);
    float* sel_lm             = (float*)(ws + OFF_LM);
    unsigned long long* sup   = (unsigned long long*)(ws + OFF_SUP);

    int tid = threadIdx.x, bid = blockIdx.x;
    int gid = bid * NTHR + tid;
    int lane = tid & 63, wv = tid >> 6;

    __shared__ union {
        int sufx[NBUCK];                      // P2..P4: counting-sort bases
        unsigned long long sup_r[1024][16];   // P6: swizzled sup matrix
    } u;
    __shared__ int swsum[16];
    __shared__ int sB;
    __shared__ unsigned long long mshare[16];
    __shared__ unsigned long long keep_final[16];

    // ---- P0: zero counters/hist/fill (fresh every call) ----
    for (int t = gid; t < NBUCK; t += GSZ) { hist[t] = 0; gfill[t] = 0; }
    if (gid < 16) ctr[gid] = 0;
    __threadfence();
    grid.sync();

    // ---- P1: softmax, threshold, wave-aggregated compact + histogram ----
    // key = (score_bits<<32) | (0xFFFFFFFF - index): descending key order ==
    // lax.top_k order (ties -> ascending index). List order nondeterministic;
    // exact ranking downstream keeps outputs deterministic.
    {
        int i = gid;
        bool pass = false;
        unsigned long long key = 0ull;
        int b = 0;
        if (i < N_ANCH) {
            float2 c = reinterpret_cast<const float2*>(conf)[i];
            float mx = fmaxf(c.x, c.y);
            float e0 = expf(c.x - mx);
            float e1 = expf(c.y - mx);
            float s  = e1 / (e0 + e1);
            if (s > CONF_THR) {
                pass = true;
                unsigned int sb = __float_as_uint(s);
                key = ((unsigned long long)sb << 32)
                    | (unsigned int)(0xFFFFFFFFu - (unsigned int)i);
                b = min((int)((sb - BUCK_BASE) >> BUCK_SHIFT), NBUCK - 1);
            }
        }
        unsigned long long mask = __ballot(pass);
        if (mask) {
            int leader = (int)__builtin_ctzll(mask);
            int base = 0;
            if (lane == leader) base = atomicAdd(&ctr[0], (int)__popcll(mask));
            base = __shfl(base, leader, 64);
            if (pass) {
                int pos = base + (int)__popcll(mask & ((1ull << lane) - 1ull));
                list[pos] = key;
                atomicAdd(&hist[b], 1);
            }
        }
    }
    __threadfence();
    grid.sync();

    int M = min(ctr[0], N_ANCH);

    // ---- P2 (every block, redundant): hist->LDS, findcut, suffix-scan ----
    for (int t = tid; t < NBUCK; t += NTHR) u.sufx[t] = hist[t];
    __syncthreads();
    // findcut (wave 0): largest B with suffix-count >= KCAP, else 0
    if (tid < 64) {
        int acc = 0, B = 0;
        bool found = false;
        for (int t = 0; t < NBUCK / 64 && !found; ++t) {
            int base = NBUCK - 64 * (t + 1);
            int c = u.sufx[base + lane];
            int ssum = c;
#pragma unroll
            for (int off = 1; off < 64; off <<= 1)
                ssum += __shfl_xor(ssum, off, 64);
            if (acc + ssum >= KCAP) {
                for (int l = 63; l >= 0; --l) {
                    int cl = (int)__builtin_amdgcn_readlane((unsigned int)c, l);
                    if (acc + cl >= KCAP) { B = base + l; found = true; break; }
                    acc += cl;
                }
            } else {
                acc += ssum;
            }
        }
        if (lane == 0) sB = found ? B : 0;
    }
    __syncthreads();
    int B = sB;
    // suffix-scan: u.sufx[b] <- #keys in buckets > b (descending segment start).
    // Thread t owns reversed positions t*5..t*5+4 (reads then writes only its
    // own entries, so no barrier needed around the writeback).
    {
        int c[5];
#pragma unroll
        for (int k = 0; k < 5; ++k)
            c[k] = u.sufx[NBUCK - 1 - (tid * 5 + k)];
        int tsum = c[0] + c[1] + c[2] + c[3] + c[4];
        int inc = tsum;
#pragma unroll
        for (int off = 1; off < 64; off <<= 1) {
            int n = __shfl_up(inc, off, 64);
            if (lane >= off) inc += n;
        }
        if (lane == 63) swsum[wv] = inc;
        __syncthreads();
        if (tid < 16) {
            int v = swsum[tid];
            int s = v;
#pragma unroll
            for (int off = 1; off < 16; off <<= 1) {
                int n = __shfl_up(s, off, 64);
                if (tid >= off) s += n;
            }
            swsum[tid] = s - v;  // exclusive wave base
        }
        __syncthreads();
        int run = swsum[wv] + inc - tsum;  // exclusive prefix (reversed order)
#pragma unroll
        for (int k = 0; k < 5; ++k) {
            u.sufx[NBUCK - 1 - (tid * 5 + k)] = run;
            run += c[k];
        }
    }
    __syncthreads();

    int S = min((B > 0) ? u.sufx[B - 1] : M, CAPG);
    int V = min(M, KCAP);

    // ---- P3: bucket-scatter kept keys (b >= B) into gkeys ----
    for (int p = gid; p < M; p += GSZ) {
        unsigned long long k = list[p];
        unsigned int sb = (unsigned int)(k >> 32);
        int b = min((int)((sb - BUCK_BASE) >> BUCK_SHIFT), NBUCK - 1);
        if (b >= B) {
            int off = atomicAdd(&gfill[b], 1);
            int slot = u.sufx[b] + off;
            if (slot < CAPG) gkeys[slot] = k;
        }
    }
    __threadfence();
    grid.sync();

    // ---- P4: exact rank (segment start + within-bucket count) + decode ----
    for (int s = gid; s < S; s += GSZ) {
        unsigned long long key = gkeys[s];
        unsigned int sb = (unsigned int)(key >> 32);
        int b = min((int)((sb - BUCK_BASE) >> BUCK_SHIFT), NBUCK - 1);
        int seg0 = u.sufx[b];
        int segn = gfill[b];
        int within = 0;
        for (int t = 0; t < segn && seg0 + t < CAPG; ++t)
            within += (gkeys[seg0 + t] > key) ? 1 : 0;
        int r = seg0 + within;
        if (r < KCAP) {
            unsigned int a = 0xFFFFFFFFu - (unsigned int)(key & 0xFFFFFFFFull);
            sel_score[r] = __uint_as_float(sb);
            float pcx = priors[a*4+0], pcy = priors[a*4+1];
            float pw  = priors[a*4+2], ph  = priors[a*4+3];
            float l0 = loc[a*4+0], l1 = loc[a*4+1], l2 = loc[a*4+2], l3 = loc[a*4+3];
            // replicate reference op order exactly:
            float cx = pcx + (l0 * 0.1f) * pw;
            float cy = pcy + (l1 * 0.1f) * ph;
            float w  = pw * expf(l2 * 0.2f);
            float h2 = ph * expf(l3 * 0.2f);
            float x1 = cx - w * 0.5f;
            float y1 = cy - h2 * 0.5f;
            sel_box[r*4+0] = x1 * 1280.0f;
            sel_box[r*4+1] = y1 * 1280.0f;
            sel_box[r*4+2] = (x1 + w) * 1280.0f;
            sel_box[r*4+3] = (y1 + h2) * 1280.0f;
#pragma unroll
            for (int q = 0; q < 5; ++q) {
                float lx = land[a*10 + 2*q + 0];
                float ly = land[a*10 + 2*q + 1];
                sel_lm[r*10 + 2*q + 0] = (pcx + (lx * 0.1f) * pw) * 1280.0f;
                sel_lm[r*10 + 2*q + 1] = (pcy + (ly * 0.1f) * ph) * 1280.0f;
            }
        }
    }
    __threadfence();
    grid.sync();

    // ---- P5: suppression bitmask rows, one wave per row ----
    {
        int i = bid * 16 + wv;   // 1056 waves cover 1000 rows
        if (i < KCAP) {
            bool irow = (i < V);
            float ax1 = 0.f, ay1 = 0.f, ax2 = 0.f, ay2 = 0.f, aarea = 0.f;
            if (irow) {
                ax1 = sel_box[i*4+0]; ay1 = sel_box[i*4+1];
                ax2 = sel_box[i*4+2]; ay2 = sel_box[i*4+3];
                aarea = (ax2 - ax1) * (ay2 - ay1);
            }
            for (int g = 0; g < 16; ++g) {
                int j = g * 64 + lane;
                bool pred = false;
                if (irow && j < V && j > i) {
                    float4 b = reinterpret_cast<const float4*>(sel_box)[j];
                    float barea = (b.z - b.x) * (b.w - b.y);
                    float ltx = fmaxf(ax1, b.x), lty = fmaxf(ay1, b.y);
                    float rbx = fminf(ax2, b.z), rby = fminf(ay2, b.w);
                    float wx = fmaxf(rbx - ltx, 0.0f);
                    float wy = fmaxf(rby - lty, 0.0f);
                    float inter = wx * wy;
                    float iou = inter / (aarea + barea - inter + 1e-12f);
                    pred = iou > NMS_THR;
                }
                unsigned long long mask = __ballot(pred);
                if (lane == 0) sup[i*16 + g] = mask;
            }
        }
    }
    __threadfence();
    grid.sync();

    // ---- P6 (block 0): sparsity-aware blocked greedy NMS scan + output ----
    // NOTE: readlane/readfirstlane return int; widen through unsigned int.
    if (bid == 0) {
        for (int idx = tid; idx < KCAP * 16; idx += NTHR) {
            int r = idx >> 4, w = idx & 15;
            u.sup_r[r][w ^ (r & 15)] = sup[idx];
        }
        if (tid < 24 * 16) { // zero rows 1000..1023
            int r = 1000 + (tid >> 4), w = tid & 15;
            u.sup_r[r][w ^ (r & 15)] = 0ull;
        }
        unsigned long long kw;
        {
            int lo = wv * 64;
            kw = (V >= lo + 64) ? ~0ull : (V <= lo ? 0ull : ((1ull << (V - lo)) - 1ull));
        }
        __syncthreads();

        for (int c = 0; c < 16; ++c) {
            if (wv == c) {
                unsigned long long drow = u.sup_r[c*64 + lane][c ^ (lane & 15)];
                unsigned int dlo = (unsigned int)drow;
                unsigned int dhi = (unsigned int)(drow >> 32);
                unsigned long long nz = __ballot(drow != 0ull);
                unsigned long long m = kw;
                unsigned long long todo = m & nz;
                while (todo) {
                    int i = (int)__builtin_ctzll(todo);
                    i = __builtin_amdgcn_readfirstlane(i);
                    unsigned long long di =
                        (((unsigned long long)(unsigned int)__builtin_amdgcn_readlane(dhi, i)) << 32)
                      |  (unsigned long long)(unsigned int)__builtin_amdgcn_readlane(dlo, i);
                    m &= ~di;            // di only holds j>i bits
                    todo &= ~di;         // suppressed rows never processed
                    todo &= todo - 1ull; // clear bit i
                }
                kw = m;
                if (lane == 0) mshare[c] = m;
            }
            __syncthreads();
            if (wv > c) {
                unsigned long long m = mshare[c];
                unsigned long long contrib = ((m >> lane) & 1ull)
                    ? u.sup_r[c*64 + lane][wv ^ (lane & 15)] : 0ull;
                if (__ballot(contrib != 0ull) != 0ull) {
#pragma unroll
                    for (int off = 1; off < 64; off <<= 1)
                        contrib |= shfl_xor_u64(contrib, off);
                    kw &= ~contrib;
                }
            }
        }
        if (lane == 0) keep_final[wv] = kw;
        __syncthreads();

        // outputs: boxes [0,4000), scores [4000,5000), landms [5000,15000)
        for (int s = tid; s < KCAP; s += NTHR) {
            bool kept = ((keep_final[s >> 6] >> (s & 63)) & 1ull) != 0ull;
            float4 b = make_float4(0.f, 0.f, 0.f, 0.f);
            float sc = 0.f;
            if (kept) {
                b  = reinterpret_cast<const float4*>(sel_box)[s];
                sc = sel_score[s];
            }
            reinterpret_cast<float4*>(out)[s] = b;
            out[4000 + s] = sc;
#pragma unroll
            for (int q = 0; q < 10; ++q)
                out[5000 + s*10 + q] = kept ? sel_lm[s*10 + q] : 0.f;
        }
    }
}

extern "C" void kernel_launch(void* const* d_in, const int* in_sizes, int n_in,
                              void* d_out, int out_size, void* d_ws, size_t ws_size,
                              hipStream_t stream) {
    const float* loc    = (const float*)d_in[0];
    const float* conf   = (const float*)d_in[1];
    const float* land   = (const float*)d_in[2];
    const float* priors = (const float*)d_in[3];
    float* out = (float*)d_out;
    char* ws = (char*)d_ws;

    void* args[] = { (void*)&loc, (void*)&conf, (void*)&land, (void*)&priors,
                     (void*)&out, (void*)&ws };
    hipLaunchCooperativeKernel((const void*)k_all, dim3(NBLK), dim3(NTHR),
                               args, 0, stream);
}

// Round 10
// 81.822 us; speedup vs baseline: 2.4703x; 2.4703x over previous
//
#include <hip/hip_runtime.h>
#include <stdint.h>

#define N_ANCH 67200
#define KCAP   1000
#define CONF_THR 0.7f
#define NMS_THR  0.4f

// score-bits histogram: scores in (0.7, 1.0] -> bits in (0x3F333333, 0x3F800000]
// span = 0x4CCCCD ulp; shift 10 -> 4917 live buckets; NBUCK = 5120 = 1024*5.
#define BUCK_BASE 0x3F333333u
#define BUCK_SHIFT 10
#define NBUCK 5120
#define CAPG 4096             // LDS bucket-sorted key capacity (kept ~ 1010)

// per-wave segments: each wave compacts 128 anchors into its own list slice
#define NSEG 528              // 525 live (525*128 = 67200) + 3 empty pad
// ---- workspace layout (bytes) ----
#define OFF_CTR    0          // int[1] = V (valid slot count)
#define OFF_SEGCNT 64         // NSEG*4 = 2112 -> 2176
#define OFF_LIST   2176       // NSEG*128*8 = 540672 -> 542848
#define OFF_SCORE  542848     // 1024*4  -> 546944
#define OFF_BOX    546944     // 1024*16 -> 563328 (16B aligned)
#define OFF_LM     563328     // 1024*40 -> 604288
#define OFF_SUP    604288     // 1000*16*8 = 128000 -> 732288 (~0.7 MB)

__device__ inline unsigned long long shfl_xor_u64(unsigned long long v, int m) {
    unsigned int lo = (unsigned int)__shfl_xor((int)(v & 0xffffffffull), m, 64);
    unsigned int hi = (unsigned int)__shfl_xor((int)(v >> 32), m, 64);
    return ((unsigned long long)hi << 32) | lo;
}

// K1: PURE front end (no atomics, nothing pre-zeroed). Each wave owns 128
// anchors; lane handles 2 via one float4 conf load; passing keys are wave-
// compacted (ballot+popcount) into the wave's own list segment; segcnt[w]
// always written (0 for pad waves). key = (score_bits<<32)|(~index):
// descending key order == lax.top_k order (ties -> ascending index).
// In-segment order is arbitrary; exact ranking downstream fixes slots.
__global__ __launch_bounds__(256) void k_front(const float* __restrict__ conf,
                                               unsigned long long* __restrict__ list,
                                               int* __restrict__ segcnt) {
    int lane = threadIdx.x & 63, wv = threadIdx.x >> 6;
    int w = blockIdx.x * 4 + wv;            // segment id, 0..527
    if (w >= NSEG) return;
    bool p0 = false, p1 = false;
    unsigned long long k0 = 0ull, k1 = 0ull;
    if (w < N_ANCH / 128) {
        float4 c = reinterpret_cast<const float4*>(conf)[w * 64 + lane];
        int a0 = w * 128 + lane * 2;
        {
            float mx = fmaxf(c.x, c.y);
            float e0 = expf(c.x - mx), e1 = expf(c.y - mx);
            float s = e1 / (e0 + e1);
            if (s > CONF_THR) {
                p0 = true;
                k0 = ((unsigned long long)__float_as_uint(s) << 32)
                   | (unsigned int)(0xFFFFFFFFu - (unsigned int)a0);
            }
        }
        {
            float mx = fmaxf(c.z, c.w);
            float e0 = expf(c.z - mx), e1 = expf(c.w - mx);
            float s = e1 / (e0 + e1);
            if (s > CONF_THR) {
                p1 = true;
                k1 = ((unsigned long long)__float_as_uint(s) << 32)
                   | (unsigned int)(0xFFFFFFFFu - (unsigned int)(a0 + 1));
            }
        }
    }
    unsigned long long m0 = __ballot(p0);
    unsigned long long m1 = __ballot(p1);
    int n0 = (int)__popcll(m0);
    unsigned long long below = (1ull << lane) - 1ull;
    int base = w * 128;
    if (p0) list[base + (int)__popcll(m0 & below)] = k0;
    if (p1) list[base + n0 + (int)__popcll(m1 & below)] = k1;
    if (lane == 0) segcnt[w] = n0 + (int)__popcll(m1);
}

// K2 (single block): segcnt->LDS (M=sum), LDS histogram over valid list
// entries, findcut, suffix-scan (counting-sort bases), bucket-scatter into
// LDS, exact rank = segment_start + within-bucket count, decode into slots.
__global__ __launch_bounds__(1024) void k_back(
        const unsigned long long* __restrict__ list,
        const int* __restrict__ segcnt,
        const float* __restrict__ loc,
        const float* __restrict__ land,
        const float* __restrict__ priors,
        int* __restrict__ ctr,
        float* __restrict__ sel_score,
        float* __restrict__ sel_box,
        float* __restrict__ sel_lm) {
#pragma clang fp contract(off)
    __shared__ int scnt[NSEG];
    __shared__ int shist[NBUCK];              // hist, then overwritten by sufx
    __shared__ int sfill[NBUCK];
    __shared__ unsigned long long sk[CAPG];   // bucket-sorted keys
    __shared__ int swsum[16];
    __shared__ int sM, sB;
    int tid = threadIdx.x;
    int lane = tid & 63, wv = tid >> 6;

    if (tid < NSEG) scnt[tid] = segcnt[tid];
    for (int t = tid; t < NBUCK; t += 1024) { shist[t] = 0; sfill[t] = 0; }
    if (tid == 0) sM = 0;
    __syncthreads();
    {   // M = sum of segment counts
        int v = (tid < NSEG) ? scnt[tid] : 0;
#pragma unroll
        for (int off = 1; off < 64; off <<= 1) v += __shfl_xor(v, off, 64);
        if (lane == 0 && v) atomicAdd(&sM, v);
    }

    // pass A: histogram of valid keys (predicated by scnt)
    for (int it = 0; it < (NSEG * 128) / 1024; ++it) {
        int slot = tid + it * 1024;
        int seg = slot >> 7, off = slot & 127;
        if (off < scnt[seg]) {
            unsigned long long k = list[slot];
            unsigned int sb = (unsigned int)(k >> 32);
            int b = min((int)((sb - BUCK_BASE) >> BUCK_SHIFT), NBUCK - 1);
            atomicAdd(&shist[b], 1);
        }
    }
    __syncthreads();
    int M = sM;

    // findcut (wave 0): largest B with suffix-count >= KCAP, else 0
    if (tid < 64) {
        int acc = 0, B = 0;
        bool found = false;
        for (int t = 0; t < NBUCK / 64 && !found; ++t) {
            int base = NBUCK - 64 * (t + 1);
            int c = shist[base + lane];
            int ssum = c;
#pragma unroll
            for (int off = 1; off < 64; off <<= 1)
                ssum += __shfl_xor(ssum, off, 64);
            if (acc + ssum >= KCAP) {
                for (int l = 63; l >= 0; --l) {
                    int cl = (int)__builtin_amdgcn_readlane((unsigned int)c, l);
                    if (acc + cl >= KCAP) { B = base + l; found = true; break; }
                    acc += cl;
                }
            } else {
                acc += ssum;
            }
        }
        if (lane == 0) sB = found ? B : 0;
    }
    __syncthreads();
    int B = sB;

    // suffix-scan: shist[b] <- #keys in buckets > b (descending segment start).
    // Thread t owns reversed positions t*5..t*5+4 (reads/writes only its own).
    {
        int c[5];
#pragma unroll
        for (int k = 0; k < 5; ++k)
            c[k] = shist[NBUCK - 1 - (tid * 5 + k)];
        int tsum = c[0] + c[1] + c[2] + c[3] + c[4];
        int inc = tsum;
#pragma unroll
        for (int off = 1; off < 64; off <<= 1) {
            int n = __shfl_up(inc, off, 64);
            if (lane >= off) inc += n;
        }
        if (lane == 63) swsum[wv] = inc;
        __syncthreads();
        if (tid < 16) {
            int v = swsum[tid];
            int s = v;
#pragma unroll
            for (int off = 1; off < 16; off <<= 1) {
                int n = __shfl_up(s, off, 64);
                if (tid >= off) s += n;
            }
            swsum[tid] = s - v;  // exclusive wave base
        }
        __syncthreads();
        int run = swsum[wv] + inc - tsum;  // exclusive prefix (reversed order)
#pragma unroll
        for (int k = 0; k < 5; ++k) {
            shist[NBUCK - 1 - (tid * 5 + k)] = run;
            run += c[k];
        }
    }
    __syncthreads();

    // pass B: bucket-scatter kept keys (b >= B) into sk (list reload, L2-hot)
    for (int it = 0; it < (NSEG * 128) / 1024; ++it) {
        int slot = tid + it * 1024;
        int seg = slot >> 7, off = slot & 127;
        if (off < scnt[seg]) {
            unsigned long long k = list[slot];
            unsigned int sb = (unsigned int)(k >> 32);
            int b = min((int)((sb - BUCK_BASE) >> BUCK_SHIFT), NBUCK - 1);
            if (b >= B) {
                int o = atomicAdd(&sfill[b], 1);
                int sl = shist[b] + o;
                if (sl < CAPG) sk[sl] = k;
            }
        }
    }
    __syncthreads();

    int S = min((B > 0) ? shist[B - 1] : M, CAPG);
    int V = min(M, KCAP);
    if (tid == 0) ctr[0] = V;

    // exact rank + decode. rank = segment_start + #same-bucket keys > mine.
    for (int s = tid; s < S; s += 1024) {
        unsigned long long key = sk[s];
        unsigned int sb = (unsigned int)(key >> 32);
        int b = min((int)((sb - BUCK_BASE) >> BUCK_SHIFT), NBUCK - 1);
        int seg0 = shist[b];
        int segn = sfill[b];
        int within = 0;
        for (int t = 0; t < segn && seg0 + t < CAPG; ++t)
            within += (sk[seg0 + t] > key) ? 1 : 0;
        int r = seg0 + within;
        if (r < KCAP) {
            unsigned int a = 0xFFFFFFFFu - (unsigned int)(key & 0xFFFFFFFFull);
            sel_score[r] = __uint_as_float(sb);
            float pcx = priors[a*4+0], pcy = priors[a*4+1];
            float pw  = priors[a*4+2], ph  = priors[a*4+3];
            float l0 = loc[a*4+0], l1 = loc[a*4+1], l2 = loc[a*4+2], l3 = loc[a*4+3];
            // replicate reference op order exactly:
            float cx = pcx + (l0 * 0.1f) * pw;
            float cy = pcy + (l1 * 0.1f) * ph;
            float w  = pw * expf(l2 * 0.2f);
            float h2 = ph * expf(l3 * 0.2f);
            float x1 = cx - w * 0.5f;
            float y1 = cy - h2 * 0.5f;
            sel_box[r*4+0] = x1 * 1280.0f;
            sel_box[r*4+1] = y1 * 1280.0f;
            sel_box[r*4+2] = (x1 + w) * 1280.0f;
            sel_box[r*4+3] = (y1 + h2) * 1280.0f;
#pragma unroll
            for (int q = 0; q < 5; ++q) {
                float lx = land[a*10 + 2*q + 0];
                float ly = land[a*10 + 2*q + 1];
                sel_lm[r*10 + 2*q + 0] = (pcx + (lx * 0.1f) * pw) * 1280.0f;
                sel_lm[r*10 + 2*q + 1] = (pcy + (ly * 0.1f) * ph) * 1280.0f;
            }
        }
    }
}

// K3: suppression bitmask rows, 4 rows per 256-thread block (250 blocks).
// sup[i][g] bit l set iff j=g*64+l satisfies j>i, both valid, iou > NMS_THR.
__global__ __launch_bounds__(256) void k_sup(const float* __restrict__ sel_box,
                                             const int* __restrict__ ctr,
                                             unsigned long long* __restrict__ sup) {
#pragma clang fp contract(off)
    int lane = threadIdx.x & 63, wv = threadIdx.x >> 6;
    int i = blockIdx.x * 4 + wv;  // 0..999
    int V = min(ctr[0], KCAP);
    bool irow = (i < V);
    float ax1 = 0.f, ay1 = 0.f, ax2 = 0.f, ay2 = 0.f, aarea = 0.f;
    if (irow) {
        ax1 = sel_box[i*4+0]; ay1 = sel_box[i*4+1];
        ax2 = sel_box[i*4+2]; ay2 = sel_box[i*4+3];
        aarea = (ax2 - ax1) * (ay2 - ay1);
    }
    for (int g = 0; g < 16; ++g) {
        int j = g * 64 + lane;
        bool pred = false;
        if (irow && j < V && j > i) {
            float4 b = reinterpret_cast<const float4*>(sel_box)[j];
            float barea = (b.z - b.x) * (b.w - b.y);
            float ltx = fmaxf(ax1, b.x), lty = fmaxf(ay1, b.y);
            float rbx = fminf(ax2, b.z), rby = fminf(ay2, b.w);
            float wx = fmaxf(rbx - ltx, 0.0f);
            float wy = fmaxf(rby - lty, 0.0f);
            float inter = wx * wy;
            float iou = inter / (aarea + barea - inter + 1e-12f);
            pred = iou > NMS_THR;
        }
        unsigned long long mask = __ballot(pred);
        if (lane == 0) sup[i*16 + g] = mask;
    }
}

// K4: blocked greedy NMS scan, sparsity-aware. NOTE: readlane/readfirstlane
// return int; widen through unsigned int (round-2 sign-extension bug).
__global__ __launch_bounds__(1024) void k_nms_scan(
        const unsigned long long* __restrict__ sup,
        const int* __restrict__ ctr,
        const float* __restrict__ sel_score,
        const float* __restrict__ sel_box,
        const float* __restrict__ sel_lm,
        float* __restrict__ out) {
    __shared__ unsigned long long sup_r[1024][16]; // [row][w ^ (row&15)]
    __shared__ unsigned long long mshare[16];
    __shared__ unsigned long long keep_final[16];
    int tid = threadIdx.x;
    int wave = tid >> 6, lane = tid & 63;
    int V = min(ctr[0], KCAP);

    for (int idx = tid; idx < KCAP * 16; idx += 1024) {
        int r = idx >> 4, w = idx & 15;
        sup_r[r][w ^ (r & 15)] = sup[idx];
    }
    if (tid < 24 * 16) { // zero rows 1000..1023
        int r = 1000 + (tid >> 4), w = tid & 15;
        sup_r[r][w ^ (r & 15)] = 0ull;
    }
    unsigned long long kw;
    {
        int lo = wave * 64;
        kw = (V >= lo + 64) ? ~0ull : (V <= lo ? 0ull : ((1ull << (V - lo)) - 1ull));
    }
    __syncthreads();

    for (int c = 0; c < 16; ++c) {
        if (wave == c) {
            unsigned long long drow = sup_r[c*64 + lane][c ^ (lane & 15)];
            unsigned int dlo = (unsigned int)drow;
            unsigned int dhi = (unsigned int)(drow >> 32);
            unsigned long long nz = __ballot(drow != 0ull);
            unsigned long long m = kw;
            unsigned long long todo = m & nz;
            while (todo) {
                int i = (int)__builtin_ctzll(todo);
                i = __builtin_amdgcn_readfirstlane(i);
                unsigned long long di =
                    (((unsigned long long)(unsigned int)__builtin_amdgcn_readlane(dhi, i)) << 32)
                  |  (unsigned long long)(unsigned int)__builtin_amdgcn_readlane(dlo, i);
                m &= ~di;            // di only holds j>i bits
                todo &= ~di;         // suppressed rows never processed
                todo &= todo - 1ull; // clear bit i
            }
            kw = m;
            if (lane == 0) mshare[c] = m;
        }
        __syncthreads();
        if (wave > c) {
            unsigned long long m = mshare[c];
            unsigned long long contrib = ((m >> lane) & 1ull)
                ? sup_r[c*64 + lane][wave ^ (lane & 15)] : 0ull;
            if (__ballot(contrib != 0ull) != 0ull) {
#pragma unroll
                for (int off = 1; off < 64; off <<= 1)
                    contrib |= shfl_xor_u64(contrib, off);
                kw &= ~contrib;
            }
        }
    }
    if (lane == 0) keep_final[wave] = kw;
    __syncthreads();

    // write outputs: boxes [0,4000), scores [4000,5000), landms [5000,15000)
    for (int s = tid; s < KCAP; s += 1024) {
        bool kept = ((keep_final[s >> 6] >> (s & 63)) & 1ull) != 0ull;
        float4 b = make_float4(0.f, 0.f, 0.f, 0.f);
        float sc = 0.f;
        if (kept) {
            b  = reinterpret_cast<const float4*>(sel_box)[s];
            sc = sel_score[s];
        }
        reinterpret_cast<float4*>(out)[s] = b;
        out[4000 + s] = sc;
#pragma unroll
        for (int q = 0; q < 10; ++q)
            out[5000 + s*10 + q] = kept ? sel_lm[s*10 + q] : 0.f;
    }
}

extern "C" void kernel_launch(void* const* d_in, const int* in_sizes, int n_in,
                              void* d_out, int out_size, void* d_ws, size_t ws_size,
                              hipStream_t stream) {
    const float* loc    = (const float*)d_in[0];
    const float* conf   = (const float*)d_in[1];
    const float* land   = (const float*)d_in[2];
    const float* priors = (const float*)d_in[3];
    float* out = (float*)d_out;
    char* ws = (char*)d_ws;

    int* ctr                     = (int*)(ws + OFF_CTR);
    int* segcnt                  = (int*)(ws + OFF_SEGCNT);
    unsigned long long* list     = (unsigned long long*)(ws + OFF_LIST);
    float* sel_score             = (float*)(ws + OFF_SCORE);
    float* sel_box               = (float*)(ws + OFF_BOX);
    float* sel_lm                = (float*)(ws + OFF_LM);
    unsigned long long* sup      = (unsigned long long*)(ws + OFF_SUP);

    k_front<<<NSEG / 4, 256, 0, stream>>>(conf, list, segcnt);
    k_back<<<1, 1024, 0, stream>>>(list, segcnt, loc, land, priors, ctr,
                                   sel_score, sel_box, sel_lm);
    k_sup<<<KCAP / 4, 256, 0, stream>>>(sel_box, ctr, sup);
    k_nms_scan<<<1, 1024, 0, stream>>>(sup, ctr, sel_score, sel_box, sel_lm, out);
}

// Round 11
// 64.958 us; speedup vs baseline: 3.1116x; 1.2596x over previous
//
#include <hip/hip_runtime.h>
#include <stdint.h>

#define N_ANCH 67200
#define KCAP   1000
#define CONF_THR 0.7f
#define NMS_THR  0.4f

// score-bits histogram: scores in (0.7, 1.0] -> bits in (0x3F333333, 0x3F800000]
// span = 0x4CCCCD ulp; shift 10 -> 4917 live buckets; NBUCK = 5120 = 1024*5.
#define BUCK_BASE 0x3F333333u
#define BUCK_SHIFT 10
#define NBUCK 5120
#define CAPG 4096             // bucket-sorted key capacity (kept ~ 1010)

#define MID_BLKS 32
#define RNK_BLKS 4

// ---- workspace layout (bytes), ~801 KB total ----
#define OFF_CTR   0           // int[0] = M (candidate count)
#define OFF_HIST  64          // +NBUCK*4 = 20480 -> 20544
#define OFF_FILL  20544       // +20480 -> 41024
#define OFF_LIST  41024       // +N_ANCH*8 = 537600 -> 578624
#define OFF_GKEYS 578624      // +CAPG*8 = 32768 -> 611392
#define OFF_SCORE 611392      // +4096 -> 615488
#define OFF_BOX   615488      // +16384 -> 631872 (16B aligned)
#define OFF_LM    631872      // +40960 -> 672832
#define OFF_SUP   672832      // +128000 -> 800832

__device__ inline unsigned long long shfl_xor_u64(unsigned long long v, int m) {
    unsigned int lo = (unsigned int)__shfl_xor((int)(v & 0xffffffffull), m, 64);
    unsigned int hi = (unsigned int)__shfl_xor((int)(v >> 32), m, 64);
    return ((unsigned long long)hi << 32) | lo;
}

__device__ inline int bucket_of(unsigned int sb) {
    return min((int)((sb - BUCK_BASE) >> BUCK_SHIFT), NBUCK - 1);
}

// Shared helper: findcut (largest B with suffix-count >= KCAP, else 0) and
// in-place suffix-scan turning hist[] into sufx[] (descending segment starts).
// Requires 1024 threads; sufx/swsum/sB in LDS. readlane returns int -> widen
// through unsigned int (round-2 sign-extension lesson).
__device__ inline void findcut_and_scan(int* sufx, int* swsum, int* sB,
                                        int tid, int lane, int wv) {
    if (tid < 64) {
        int acc = 0, B = 0;
        bool found = false;
        for (int t = 0; t < NBUCK / 64 && !found; ++t) {
            int base = NBUCK - 64 * (t + 1);
            int c = sufx[base + lane];
            int ssum = c;
#pragma unroll
            for (int off = 1; off < 64; off <<= 1)
                ssum += __shfl_xor(ssum, off, 64);
            if (acc + ssum >= KCAP) {
                for (int l = 63; l >= 0; --l) {
                    int cl = (int)__builtin_amdgcn_readlane((unsigned int)c, l);
                    if (acc + cl >= KCAP) { B = base + l; found = true; break; }
                    acc += cl;
                }
            } else {
                acc += ssum;
            }
        }
        if (lane == 0) *sB = found ? B : 0;
    }
    __syncthreads();
    // suffix-scan: sufx[b] <- #keys in buckets > b. Thread t owns reversed
    // positions t*5..t*5+4 (reads/writes only its own entries).
    int c[5];
#pragma unroll
    for (int k = 0; k < 5; ++k)
        c[k] = sufx[NBUCK - 1 - (tid * 5 + k)];
    int tsum = c[0] + c[1] + c[2] + c[3] + c[4];
    int inc = tsum;
#pragma unroll
    for (int off = 1; off < 64; off <<= 1) {
        int n = __shfl_up(inc, off, 64);
        if (lane >= off) inc += n;
    }
    if (lane == 63) swsum[wv] = inc;
    __syncthreads();
    if (tid < 16) {
        int v = swsum[tid];
        int s = v;
#pragma unroll
        for (int off = 1; off < 16; off <<= 1) {
            int n = __shfl_up(s, off, 64);
            if (tid >= off) s += n;
        }
        swsum[tid] = s - v;  // exclusive wave base
    }
    __syncthreads();
    int run = swsum[wv] + inc - tsum;  // exclusive prefix (reversed order)
#pragma unroll
    for (int k = 0; k < 5; ++k) {
        sufx[NBUCK - 1 - (tid * 5 + k)] = run;
        run += c[k];
    }
    __syncthreads();
}

// K0: zero counters + histogram + fill (dedicated; rocclr fill costs 40us).
__global__ __launch_bounds__(1024) void k_zero(int* __restrict__ ctr,
                                               int* __restrict__ hist,
                                               int* __restrict__ gfill) {
    int tid = threadIdx.x;
    if (tid < 16) ctr[tid] = 0;
    for (int t = tid; t < NBUCK; t += 1024) { hist[t] = 0; gfill[t] = 0; }
}

// K1: softmax, threshold, wave-aggregated DENSE compact + histogram.
// key = (score_bits<<32) | (0xFFFFFFFF - index): descending key order ==
// lax.top_k order (ties -> ascending index). List order nondeterministic;
// exact ranking downstream keeps outputs deterministic.
__global__ __launch_bounds__(256) void k_front(const float* __restrict__ conf,
                                               unsigned long long* __restrict__ list,
                                               int* __restrict__ hist,
                                               int* __restrict__ ctr) {
    int t = blockIdx.x * 256 + threadIdx.x;   // float4 index = 2 anchors
    int lane = threadIdx.x & 63;
    int a0 = t * 2;
    bool p0 = false, p1 = false;
    unsigned long long k0 = 0ull, k1 = 0ull;
    if (a0 < N_ANCH) {
        float4 c = reinterpret_cast<const float4*>(conf)[t];
        {
            float mx = fmaxf(c.x, c.y);
            float e0 = expf(c.x - mx), e1 = expf(c.y - mx);
            float s = e1 / (e0 + e1);
            if (s > CONF_THR) {
                p0 = true;
                k0 = ((unsigned long long)__float_as_uint(s) << 32)
                   | (unsigned int)(0xFFFFFFFFu - (unsigned int)a0);
            }
        }
        {
            float mx = fmaxf(c.z, c.w);
            float e0 = expf(c.z - mx), e1 = expf(c.w - mx);
            float s = e1 / (e0 + e1);
            if (s > CONF_THR) {
                p1 = true;
                k1 = ((unsigned long long)__float_as_uint(s) << 32)
                   | (unsigned int)(0xFFFFFFFFu - (unsigned int)(a0 + 1));
            }
        }
    }
    unsigned long long m0 = __ballot(p0);
    unsigned long long m1 = __ballot(p1);
    int n0 = (int)__popcll(m0), n1 = (int)__popcll(m1);
    int base = 0;
    if ((n0 + n1) > 0) {
        if (lane == 0) base = atomicAdd(&ctr[0], n0 + n1);
        base = __shfl(base, 0, 64);
        unsigned long long below = (1ull << lane) - 1ull;
        if (p0) {
            list[base + (int)__popcll(m0 & below)] = k0;
            atomicAdd(&hist[bucket_of((unsigned int)(k0 >> 32))], 1);
        }
        if (p1) {
            list[base + n0 + (int)__popcll(m1 & below)] = k1;
            atomicAdd(&hist[bucket_of((unsigned int)(k1 >> 32))], 1);
        }
    }
}

// K2 (parallel filter): each block redundantly computes findcut + sufx from
// hist, then scatters its slice's kept keys (b >= B) into bucket-sorted gkeys
// via global gfill atomics. O(M) work spread over MID_BLKS CUs.
__global__ __launch_bounds__(1024) void k_mid(
        const unsigned long long* __restrict__ list,
        const int* __restrict__ hist,
        int* __restrict__ gfill,
        unsigned long long* __restrict__ gkeys,
        const int* __restrict__ ctr) {
    __shared__ int sufx[NBUCK];
    __shared__ int swsum[16];
    __shared__ int sB;
    int tid = threadIdx.x, lane = tid & 63, wv = tid >> 6;
    for (int t = tid; t < NBUCK; t += 1024) sufx[t] = hist[t];
    __syncthreads();
    findcut_and_scan(sufx, swsum, &sB, tid, lane, wv);
    int B = sB;
    int M = min(ctr[0], N_ANCH);
    for (int p = blockIdx.x * 1024 + tid; p < M; p += MID_BLKS * 1024) {
        unsigned long long k = list[p];
        int b = bucket_of((unsigned int)(k >> 32));
        if (b >= B) {
            int off = atomicAdd(&gfill[b], 1);
            int slot = sufx[b] + off;
            if (slot < CAPG) gkeys[slot] = k;
        }
    }
}

// K3 (parallel rank+decode): exact rank = segment start + #same-bucket keys
// greater than mine (L2-hot, ~4 compares), then decode into slot r.
__global__ __launch_bounds__(1024) void k_rankdec(
        const unsigned long long* __restrict__ gkeys,
        const int* __restrict__ hist,
        const int* __restrict__ gfill,
        const int* __restrict__ ctr,
        const float* __restrict__ loc,
        const float* __restrict__ land,
        const float* __restrict__ priors,
        float* __restrict__ sel_score,
        float* __restrict__ sel_box,
        float* __restrict__ sel_lm) {
#pragma clang fp contract(off)
    __shared__ int sufx[NBUCK];
    __shared__ int swsum[16];
    __shared__ int sB;
    int tid = threadIdx.x, lane = tid & 63, wv = tid >> 6;
    for (int t = tid; t < NBUCK; t += 1024) sufx[t] = hist[t];
    __syncthreads();
    findcut_and_scan(sufx, swsum, &sB, tid, lane, wv);
    int B = sB;
    int M = min(ctr[0], N_ANCH);
    int S = min((B > 0) ? sufx[B - 1] : M, CAPG);

    for (int s = blockIdx.x * 1024 + tid; s < S; s += RNK_BLKS * 1024) {
        unsigned long long key = gkeys[s];
        unsigned int sb = (unsigned int)(key >> 32);
        int b = bucket_of(sb);
        int seg0 = sufx[b];
        int segn = gfill[b];
        int within = 0;
        for (int t = 0; t < segn && seg0 + t < CAPG; ++t)
            within += (gkeys[seg0 + t] > key) ? 1 : 0;
        int r = seg0 + within;
        if (r < KCAP) {
            unsigned int a = 0xFFFFFFFFu - (unsigned int)(key & 0xFFFFFFFFull);
            sel_score[r] = __uint_as_float(sb);
            float pcx = priors[a*4+0], pcy = priors[a*4+1];
            float pw  = priors[a*4+2], ph  = priors[a*4+3];
            float l0 = loc[a*4+0], l1 = loc[a*4+1], l2 = loc[a*4+2], l3 = loc[a*4+3];
            // replicate reference op order exactly:
            float cx = pcx + (l0 * 0.1f) * pw;
            float cy = pcy + (l1 * 0.1f) * ph;
            float w  = pw * expf(l2 * 0.2f);
            float h2 = ph * expf(l3 * 0.2f);
            float x1 = cx - w * 0.5f;
            float y1 = cy - h2 * 0.5f;
            sel_box[r*4+0] = x1 * 1280.0f;
            sel_box[r*4+1] = y1 * 1280.0f;
            sel_box[r*4+2] = (x1 + w) * 1280.0f;
            sel_box[r*4+3] = (y1 + h2) * 1280.0f;
#pragma unroll
            for (int q = 0; q < 5; ++q) {
                float lx = land[a*10 + 2*q + 0];
                float ly = land[a*10 + 2*q + 1];
                sel_lm[r*10 + 2*q + 0] = (pcx + (lx * 0.1f) * pw) * 1280.0f;
                sel_lm[r*10 + 2*q + 1] = (pcy + (ly * 0.1f) * ph) * 1280.0f;
            }
        }
    }
}

// K4: suppression bitmask rows, 4 rows per 256-thread block (250 blocks).
__global__ __launch_bounds__(256) void k_sup(const float* __restrict__ sel_box,
                                             const int* __restrict__ ctr,
                                             unsigned long long* __restrict__ sup) {
#pragma clang fp contract(off)
    int lane = threadIdx.x & 63, wv = threadIdx.x >> 6;
    int i = blockIdx.x * 4 + wv;  // 0..999
    int V = min(ctr[0], KCAP);
    bool irow = (i < V);
    float ax1 = 0.f, ay1 = 0.f, ax2 = 0.f, ay2 = 0.f, aarea = 0.f;
    if (irow) {
        ax1 = sel_box[i*4+0]; ay1 = sel_box[i*4+1];
        ax2 = sel_box[i*4+2]; ay2 = sel_box[i*4+3];
        aarea = (ax2 - ax1) * (ay2 - ay1);
    }
    for (int g = 0; g < 16; ++g) {
        int j = g * 64 + lane;
        bool pred = false;
        if (irow && j < V && j > i) {
            float4 b = reinterpret_cast<const float4*>(sel_box)[j];
            float barea = (b.z - b.x) * (b.w - b.y);
            float ltx = fmaxf(ax1, b.x), lty = fmaxf(ay1, b.y);
            float rbx = fminf(ax2, b.z), rby = fminf(ay2, b.w);
            float wx = fmaxf(rbx - ltx, 0.0f);
            float wy = fmaxf(rby - lty, 0.0f);
            float inter = wx * wy;
            float iou = inter / (aarea + barea - inter + 1e-12f);
            pred = iou > NMS_THR;
        }
        unsigned long long mask = __ballot(pred);
        if (lane == 0) sup[i*16 + g] = mask;
    }
}

// K5: blocked greedy NMS scan, sparsity-aware (proven r6 version).
__global__ __launch_bounds__(1024) void k_nms_scan(
        const unsigned long long* __restrict__ sup,
        const int* __restrict__ ctr,
        const float* __restrict__ sel_score,
        const float* __restrict__ sel_box,
        const float* __restrict__ sel_lm,
        float* __restrict__ out) {
    __shared__ unsigned long long sup_r[1024][16]; // [row][w ^ (row&15)]
    __shared__ unsigned long long mshare[16];
    __shared__ unsigned long long keep_final[16];
    int tid = threadIdx.x;
    int wave = tid >> 6, lane = tid & 63;
    int V = min(ctr[0], KCAP);

    for (int idx = tid; idx < KCAP * 16; idx += 1024) {
        int r = idx >> 4, w = idx & 15;
        sup_r[r][w ^ (r & 15)] = sup[idx];
    }
    if (tid < 24 * 16) { // zero rows 1000..1023
        int r = 1000 + (tid >> 4), w = tid & 15;
        sup_r[r][w ^ (r & 15)] = 0ull;
    }
    unsigned long long kw;
    {
        int lo = wave * 64;
        kw = (V >= lo + 64) ? ~0ull : (V <= lo ? 0ull : ((1ull << (V - lo)) - 1ull));
    }
    __syncthreads();

    for (int c = 0; c < 16; ++c) {
        if (wave == c) {
            unsigned long long drow = sup_r[c*64 + lane][c ^ (lane & 15)];
            unsigned int dlo = (unsigned int)drow;
            unsigned int dhi = (unsigned int)(drow >> 32);
            unsigned long long nz = __ballot(drow != 0ull);
            unsigned long long m = kw;
            unsigned long long todo = m & nz;
            while (todo) {
                int i = (int)__builtin_ctzll(todo);
                i = __builtin_amdgcn_readfirstlane(i);
                unsigned long long di =
                    (((unsigned long long)(unsigned int)__builtin_amdgcn_readlane(dhi, i)) << 32)
                  |  (unsigned long long)(unsigned int)__builtin_amdgcn_readlane(dlo, i);
                m &= ~di;            // di only holds j>i bits
                todo &= ~di;         // suppressed rows never processed
                todo &= todo - 1ull; // clear bit i
            }
            kw = m;
            if (lane == 0) mshare[c] = m;
        }
        __syncthreads();
        if (wave > c) {
            unsigned long long m = mshare[c];
            unsigned long long contrib = ((m >> lane) & 1ull)
                ? sup_r[c*64 + lane][wave ^ (lane & 15)] : 0ull;
            if (__ballot(contrib != 0ull) != 0ull) {
#pragma unroll
                for (int off = 1; off < 64; off <<= 1)
                    contrib |= shfl_xor_u64(contrib, off);
                kw &= ~contrib;
            }
        }
    }
    if (lane == 0) keep_final[wave] = kw;
    __syncthreads();

    // write outputs: boxes [0,4000), scores [4000,5000), landms [5000,15000)
    for (int s = tid; s < KCAP; s += 1024) {
        bool kept = ((keep_final[s >> 6] >> (s & 63)) & 1ull) != 0ull;
        float4 b = make_float4(0.f, 0.f, 0.f, 0.f);
        float sc = 0.f;
        if (kept) {
            b  = reinterpret_cast<const float4*>(sel_box)[s];
            sc = sel_score[s];
        }
        reinterpret_cast<float4*>(out)[s] = b;
        out[4000 + s] = sc;
#pragma unroll
        for (int q = 0; q < 10; ++q)
            out[5000 + s*10 + q] = kept ? sel_lm[s*10 + q] : 0.f;
    }
}

extern "C" void kernel_launch(void* const* d_in, const int* in_sizes, int n_in,
                              void* d_out, int out_size, void* d_ws, size_t ws_size,
                              hipStream_t stream) {
    const float* loc    = (const float*)d_in[0];
    const float* conf   = (const float*)d_in[1];
    const float* land   = (const float*)d_in[2];
    const float* priors = (const float*)d_in[3];
    float* out = (float*)d_out;
    char* ws = (char*)d_ws;

    int* ctr                     = (int*)(ws + OFF_CTR);
    int* hist                    = (int*)(ws + OFF_HIST);
    int* gfill                   = (int*)(ws + OFF_FILL);
    unsigned long long* list     = (unsigned long long*)(ws + OFF_LIST);
    unsigned long long* gkeys    = (unsigned long long*)(ws + OFF_GKEYS);
    float* sel_score             = (float*)(ws + OFF_SCORE);
    float* sel_box               = (float*)(ws + OFF_BOX);
    float* sel_lm                = (float*)(ws + OFF_LM);
    unsigned long long* sup      = (unsigned long long*)(ws + OFF_SUP);

    int nfb = (N_ANCH / 2 + 255) / 256; // 132
    k_zero<<<1, 1024, 0, stream>>>(ctr, hist, gfill);
    k_front<<<nfb, 256, 0, stream>>>(conf, list, hist, ctr);
    k_mid<<<MID_BLKS, 1024, 0, stream>>>(list, hist, gfill, gkeys, ctr);
    k_rankdec<<<RNK_BLKS, 1024, 0, stream>>>(gkeys, hist, gfill, ctr,
                                             loc, land, priors,
                                             sel_score, sel_box, sel_lm);
    k_sup<<<KCAP / 4, 256, 0, stream>>>(sel_box, ctr, sup);
    k_nms_scan<<<1, 1024, 0, stream>>>(sup, ctr, sel_score, sel_box, sel_lm, out);
}

// Round 12
// 60.298 us; speedup vs baseline: 3.3521x; 1.0773x over previous
//
#include <hip/hip_runtime.h>
#include <stdint.h>

#define N_ANCH 67200
#define KCAP   1000
#define CONF_THR 0.7f
#define NMS_THR  0.4f

// score-bits histogram: scores in (0.7, 1.0] -> bits in (0x3F333333, 0x3F800000]
// span = 0x4CCCCD ulp; shift 10 -> 4917 live buckets; NBUCK = 5120 = 1024*5.
#define BUCK_BASE 0x3F333333u
#define BUCK_SHIFT 10
#define NBUCK 5120
#define CAPG 4096             // bucket-sorted key capacity (kept ~ 1010)

#define MID_BLKS 32
#define SUP_BLKS 63           // 63*16 = 1008 rows >= KCAP

// ---- workspace layout (bytes), ~801 KB total ----
#define OFF_CTR   0           // [0]=M, [1]=done_mid, [2]=done_sup
#define OFF_HIST  64          // +NBUCK*4 = 20480 -> 20544
#define OFF_FILL  20544       // +20480 -> 41024
#define OFF_LIST  41024       // +N_ANCH*8 = 537600 -> 578624
#define OFF_GKEYS 578624      // +CAPG*8 = 32768 -> 611392
#define OFF_SCORE 611392      // +4096 -> 615488
#define OFF_BOX   615488      // +16384 -> 631872 (16B aligned)
#define OFF_LM    631872      // +40960 -> 672832
#define OFF_SUP   672832      // +128000 -> 800832

__device__ inline unsigned long long shfl_xor_u64(unsigned long long v, int m) {
    unsigned int lo = (unsigned int)__shfl_xor((int)(v & 0xffffffffull), m, 64);
    unsigned int hi = (unsigned int)__shfl_xor((int)(v >> 32), m, 64);
    return ((unsigned long long)hi << 32) | lo;
}

__device__ inline int bucket_of(unsigned int sb) {
    return min((int)((sb - BUCK_BASE) >> BUCK_SHIFT), NBUCK - 1);
}

// findcut (largest B with suffix-count >= KCAP, else 0) + in-place suffix
// scan turning hist[] into sufx[] (descending segment starts). 1024 threads.
// readlane returns int -> widen through unsigned int (round-2 lesson).
__device__ inline void findcut_and_scan(int* sufx, int* swsum, int* sB,
                                        int tid, int lane, int wv) {
    if (tid < 64) {
        int acc = 0, B = 0;
        bool found = false;
        for (int t = 0; t < NBUCK / 64 && !found; ++t) {
            int base = NBUCK - 64 * (t + 1);
            int c = sufx[base + lane];
            int ssum = c;
#pragma unroll
            for (int off = 1; off < 64; off <<= 1)
                ssum += __shfl_xor(ssum, off, 64);
            if (acc + ssum >= KCAP) {
                for (int l = 63; l >= 0; --l) {
                    int cl = (int)__builtin_amdgcn_readlane((unsigned int)c, l);
                    if (acc + cl >= KCAP) { B = base + l; found = true; break; }
                    acc += cl;
                }
            } else {
                acc += ssum;
            }
        }
        if (lane == 0) *sB = found ? B : 0;
    }
    __syncthreads();
    int c[5];
#pragma unroll
    for (int k = 0; k < 5; ++k)
        c[k] = sufx[NBUCK - 1 - (tid * 5 + k)];
    int tsum = c[0] + c[1] + c[2] + c[3] + c[4];
    int inc = tsum;
#pragma unroll
    for (int off = 1; off < 64; off <<= 1) {
        int n = __shfl_up(inc, off, 64);
        if (lane >= off) inc += n;
    }
    if (lane == 63) swsum[wv] = inc;
    __syncthreads();
    if (tid < 16) {
        int v = swsum[tid];
        int s = v;
#pragma unroll
        for (int off = 1; off < 16; off <<= 1) {
            int n = __shfl_up(s, off, 64);
            if (tid >= off) s += n;
        }
        swsum[tid] = s - v;  // exclusive wave base
    }
    __syncthreads();
    int run = swsum[wv] + inc - tsum;  // exclusive prefix (reversed order)
#pragma unroll
    for (int k = 0; k < 5; ++k) {
        sufx[NBUCK - 1 - (tid * 5 + k)] = run;
        run += c[k];
    }
    __syncthreads();
}

// K0: zero counters + histogram + fill (rocclr fill is pathological: 40us).
__global__ __launch_bounds__(1024) void k_zero(int* __restrict__ ctr,
                                               int* __restrict__ hist,
                                               int* __restrict__ gfill) {
    int tid = threadIdx.x;
    if (tid < 16) ctr[tid] = 0;
    for (int t = tid; t < NBUCK; t += 1024) { hist[t] = 0; gfill[t] = 0; }
}

// K1: softmax, threshold, wave-aggregated dense compact + histogram.
// key = (score_bits<<32) | (0xFFFFFFFF - index): descending key order ==
// lax.top_k order (ties -> ascending index). List order nondeterministic;
// exact ranking downstream keeps outputs deterministic.
__global__ __launch_bounds__(256) void k_front(const float* __restrict__ conf,
                                               unsigned long long* __restrict__ list,
                                               int* __restrict__ hist,
                                               int* __restrict__ ctr) {
    int t = blockIdx.x * 256 + threadIdx.x;   // float4 index = 2 anchors
    int lane = threadIdx.x & 63;
    int a0 = t * 2;
    bool p0 = false, p1 = false;
    unsigned long long k0 = 0ull, k1 = 0ull;
    if (a0 < N_ANCH) {
        float4 c = reinterpret_cast<const float4*>(conf)[t];
        {
            float mx = fmaxf(c.x, c.y);
            float e0 = expf(c.x - mx), e1 = expf(c.y - mx);
            float s = e1 / (e0 + e1);
            if (s > CONF_THR) {
                p0 = true;
                k0 = ((unsigned long long)__float_as_uint(s) << 32)
                   | (unsigned int)(0xFFFFFFFFu - (unsigned int)a0);
            }
        }
        {
            float mx = fmaxf(c.z, c.w);
            float e0 = expf(c.z - mx), e1 = expf(c.w - mx);
            float s = e1 / (e0 + e1);
            if (s > CONF_THR) {
                p1 = true;
                k1 = ((unsigned long long)__float_as_uint(s) << 32)
                   | (unsigned int)(0xFFFFFFFFu - (unsigned int)(a0 + 1));
            }
        }
    }
    unsigned long long m0 = __ballot(p0);
    unsigned long long m1 = __ballot(p1);
    int n0 = (int)__popcll(m0), n1 = (int)__popcll(m1);
    int base = 0;
    if ((n0 + n1) > 0) {
        if (lane == 0) base = atomicAdd(&ctr[0], n0 + n1);
        base = __shfl(base, 0, 64);
        unsigned long long below = (1ull << lane) - 1ull;
        if (p0) {
            list[base + (int)__popcll(m0 & below)] = k0;
            atomicAdd(&hist[bucket_of((unsigned int)(k0 >> 32))], 1);
        }
        if (p1) {
            list[base + n0 + (int)__popcll(m1 & below)] = k1;
            atomicAdd(&hist[bucket_of((unsigned int)(k1 >> 32))], 1);
        }
    }
}

// K2: parallel filter-scatter + last-block rank+decode. Each of MID_BLKS
// blocks computes findcut+sufx from hist, scatters its slice of kept keys
// (b >= B) into bucket-sorted gkeys. The LAST block to finish (device-scope
// done counter + threadfence release/acquire) ranks & decodes all S keys,
// reusing its LDS sufx. Exact rank -> deterministic output slots.
__global__ __launch_bounds__(1024) void k_midrank(
        const unsigned long long* __restrict__ list,
        const int* __restrict__ hist,
        int* __restrict__ gfill,
        unsigned long long* __restrict__ gkeys,
        int* __restrict__ ctr,
        const float* __restrict__ loc,
        const float* __restrict__ land,
        const float* __restrict__ priors,
        float* __restrict__ sel_score,
        float* __restrict__ sel_box,
        float* __restrict__ sel_lm) {
#pragma clang fp contract(off)
    __shared__ int sufx[NBUCK];
    __shared__ int swsum[16];
    __shared__ int sB;
    __shared__ int slast;
    int tid = threadIdx.x, lane = tid & 63, wv = tid >> 6;
    for (int t = tid; t < NBUCK; t += 1024) sufx[t] = hist[t];
    __syncthreads();
    findcut_and_scan(sufx, swsum, &sB, tid, lane, wv);
    int B = sB;
    int M = min(ctr[0], N_ANCH);

    for (int p = blockIdx.x * 1024 + tid; p < M; p += MID_BLKS * 1024) {
        unsigned long long k = list[p];
        int b = bucket_of((unsigned int)(k >> 32));
        if (b >= B) {
            int off = atomicAdd(&gfill[b], 1);
            int slot = sufx[b] + off;
            if (slot < CAPG) gkeys[slot] = k;
        }
    }
    __syncthreads();               // all block stores issued+drained
    if (tid == 0) {
        __threadfence();           // release: make scatter visible device-wide
        int old = atomicAdd(&ctr[1], 1);
        slast = (old == MID_BLKS - 1);
    }
    __syncthreads();
    if (!slast) return;
    if (tid == 0) __threadfence(); // acquire: invalidate stale cache
    __syncthreads();

    int S = min((B > 0) ? sufx[B - 1] : M, CAPG);
    for (int s = tid; s < S; s += 1024) {
        unsigned long long key = gkeys[s];
        unsigned int sb = (unsigned int)(key >> 32);
        int b = bucket_of(sb);
        int seg0 = sufx[b];
        int segn = gfill[b];
        int within = 0;
        for (int t = 0; t < segn && seg0 + t < CAPG; ++t)
            within += (gkeys[seg0 + t] > key) ? 1 : 0;
        int r = seg0 + within;
        if (r < KCAP) {
            unsigned int a = 0xFFFFFFFFu - (unsigned int)(key & 0xFFFFFFFFull);
            sel_score[r] = __uint_as_float(sb);
            float pcx = priors[a*4+0], pcy = priors[a*4+1];
            float pw  = priors[a*4+2], ph  = priors[a*4+3];
            float l0 = loc[a*4+0], l1 = loc[a*4+1], l2 = loc[a*4+2], l3 = loc[a*4+3];
            // replicate reference op order exactly:
            float cx = pcx + (l0 * 0.1f) * pw;
            float cy = pcy + (l1 * 0.1f) * ph;
            float w  = pw * expf(l2 * 0.2f);
            float h2 = ph * expf(l3 * 0.2f);
            float x1 = cx - w * 0.5f;
            float y1 = cy - h2 * 0.5f;
            sel_box[r*4+0] = x1 * 1280.0f;
            sel_box[r*4+1] = y1 * 1280.0f;
            sel_box[r*4+2] = (x1 + w) * 1280.0f;
            sel_box[r*4+3] = (y1 + h2) * 1280.0f;
#pragma unroll
            for (int q = 0; q < 5; ++q) {
                float lx = land[a*10 + 2*q + 0];
                float ly = land[a*10 + 2*q + 1];
                sel_lm[r*10 + 2*q + 0] = (pcx + (lx * 0.1f) * pw) * 1280.0f;
                sel_lm[r*10 + 2*q + 1] = (pcy + (ly * 0.1f) * ph) * 1280.0f;
            }
        }
    }
}

// K3: sup matrix (16 rows per 1024-thread block, 63 blocks) + last-block
// sparse greedy scan + output write. Same release/acquire done-counter.
__global__ __launch_bounds__(1024) void k_supscan(
        const float* __restrict__ sel_box,
        const float* __restrict__ sel_score,
        const float* __restrict__ sel_lm,
        int* __restrict__ ctr,
        unsigned long long* __restrict__ sup,
        float* __restrict__ out) {
#pragma clang fp contract(off)
    __shared__ unsigned long long sup_r[1024][16]; // [row][w ^ (row&15)]
    __shared__ unsigned long long mshare[16];
    __shared__ unsigned long long keep_final[16];
    __shared__ int slast;
    int tid = threadIdx.x;
    int wave = tid >> 6, lane = tid & 63;
    int V = min(ctr[0], KCAP);

    // ---- sup phase: wave handles row i ----
    {
        int i = blockIdx.x * 16 + wave;  // 0..1007
        if (i < KCAP) {
            bool irow = (i < V);
            float ax1 = 0.f, ay1 = 0.f, ax2 = 0.f, ay2 = 0.f, aarea = 0.f;
            if (irow) {
                ax1 = sel_box[i*4+0]; ay1 = sel_box[i*4+1];
                ax2 = sel_box[i*4+2]; ay2 = sel_box[i*4+3];
                aarea = (ax2 - ax1) * (ay2 - ay1);
            }
            for (int g = 0; g < 16; ++g) {
                int j = g * 64 + lane;
                bool pred = false;
                if (irow && j < V && j > i) {
                    float4 b = reinterpret_cast<const float4*>(sel_box)[j];
                    float barea = (b.z - b.x) * (b.w - b.y);
                    float ltx = fmaxf(ax1, b.x), lty = fmaxf(ay1, b.y);
                    float rbx = fminf(ax2, b.z), rby = fminf(ay2, b.w);
                    float wx = fmaxf(rbx - ltx, 0.0f);
                    float wy = fmaxf(rby - lty, 0.0f);
                    float inter = wx * wy;
                    float iou = inter / (aarea + barea - inter + 1e-12f);
                    pred = iou > NMS_THR;
                }
                unsigned long long mask = __ballot(pred);
                if (lane == 0) sup[i*16 + g] = mask;
            }
        }
    }
    __syncthreads();               // all block stores drained
    if (tid == 0) {
        __threadfence();           // release
        int old = atomicAdd(&ctr[2], 1);
        slast = (old == SUP_BLKS - 1);
    }
    __syncthreads();
    if (!slast) return;
    if (tid == 0) __threadfence(); // acquire
    __syncthreads();

    // ---- scan phase (last block only): proven sparse resolve ----
    for (int idx = tid; idx < KCAP * 16; idx += 1024) {
        int r = idx >> 4, w = idx & 15;
        sup_r[r][w ^ (r & 15)] = sup[idx];
    }
    if (tid < 24 * 16) { // zero rows 1000..1023
        int r = 1000 + (tid >> 4), w = tid & 15;
        sup_r[r][w ^ (r & 15)] = 0ull;
    }
    unsigned long long kw;
    {
        int lo = wave * 64;
        kw = (V >= lo + 64) ? ~0ull : (V <= lo ? 0ull : ((1ull << (V - lo)) - 1ull));
    }
    __syncthreads();

    for (int c = 0; c < 16; ++c) {
        if (wave == c) {
            unsigned long long drow = sup_r[c*64 + lane][c ^ (lane & 15)];
            unsigned int dlo = (unsigned int)drow;
            unsigned int dhi = (unsigned int)(drow >> 32);
            unsigned long long nz = __ballot(drow != 0ull);
            unsigned long long m = kw;
            unsigned long long todo = m & nz;
            while (todo) {
                int i = (int)__builtin_ctzll(todo);
                i = __builtin_amdgcn_readfirstlane(i);
                unsigned long long di =
                    (((unsigned long long)(unsigned int)__builtin_amdgcn_readlane(dhi, i)) << 32)
                  |  (unsigned long long)(unsigned int)__builtin_amdgcn_readlane(dlo, i);
                m &= ~di;            // di only holds j>i bits
                todo &= ~di;         // suppressed rows never processed
                todo &= todo - 1ull; // clear bit i
            }
            kw = m;
            if (lane == 0) mshare[c] = m;
        }
        __syncthreads();
        if (wave > c) {
            unsigned long long m = mshare[c];
            unsigned long long contrib = ((m >> lane) & 1ull)
                ? sup_r[c*64 + lane][wave ^ (lane & 15)] : 0ull;
            if (__ballot(contrib != 0ull) != 0ull) {
#pragma unroll
                for (int off = 1; off < 64; off <<= 1)
                    contrib |= shfl_xor_u64(contrib, off);
                kw &= ~contrib;
            }
        }
    }
    if (lane == 0) keep_final[wave] = kw;
    __syncthreads();

    // outputs: boxes [0,4000), scores [4000,5000), landms [5000,15000)
    for (int s = tid; s < KCAP; s += 1024) {
        bool kept = ((keep_final[s >> 6] >> (s & 63)) & 1ull) != 0ull;
        float4 b = make_float4(0.f, 0.f, 0.f, 0.f);
        float sc = 0.f;
        if (kept) {
            b  = reinterpret_cast<const float4*>(sel_box)[s];
            sc = sel_score[s];
        }
        reinterpret_cast<float4*>(out)[s] = b;
        out[4000 + s] = sc;
#pragma unroll
        for (int q = 0; q < 10; ++q)
            out[5000 + s*10 + q] = kept ? sel_lm[s*10 + q] : 0.f;
    }
}

extern "C" void kernel_launch(void* const* d_in, const int* in_sizes, int n_in,
                              void* d_out, int out_size, void* d_ws, size_t ws_size,
                              hipStream_t stream) {
    const float* loc    = (const float*)d_in[0];
    const float* conf   = (const float*)d_in[1];
    const float* land   = (const float*)d_in[2];
    const float* priors = (const float*)d_in[3];
    float* out = (float*)d_out;
    char* ws = (char*)d_ws;

    int* ctr                     = (int*)(ws + OFF_CTR);
    int* hist                    = (int*)(ws + OFF_HIST);
    int* gfill                   = (int*)(ws + OFF_FILL);
    unsigned long long* list     = (unsigned long long*)(ws + OFF_LIST);
    unsigned long long* gkeys    = (unsigned long long*)(ws + OFF_GKEYS);
    float* sel_score             = (float*)(ws + OFF_SCORE);
    float* sel_box               = (float*)(ws + OFF_BOX);
    float* sel_lm                = (float*)(ws + OFF_LM);
    unsigned long long* sup      = (unsigned long long*)(ws + OFF_SUP);

    int nfb = (N_ANCH / 2 + 255) / 256; // 132
    k_zero<<<1, 1024, 0, stream>>>(ctr, hist, gfill);
    k_front<<<nfb, 256, 0, stream>>>(conf, list, hist, ctr);
    k_midrank<<<MID_BLKS, 1024, 0, stream>>>(list, hist, gfill, gkeys, ctr,
                                             loc, land, priors,
                                             sel_score, sel_box, sel_lm);
    k_supscan<<<SUP_BLKS, 1024, 0, stream>>>(sel_box, sel_score, sel_lm, ctr,
                                             sup, out);
}